// Round 10
// baseline (192.894 us; speedup 1.0000x reference)
//
#include <hip/hip_runtime.h>

// Sinkhorn loss, single-pass moment formulation.
//   s_t = relu(v_t); X_t = cumsum(s); Sx = sum_t X_t
//   loss_p = sum_t t * (X_t/Sx - Y_t/Sy)^2 ;  out = sum_p loss_p
// Chunk j (LCH=32 rows; local cumsums L,M; exclusive offsets O,P):
//   sum_{t in j} t*(isx*X - isy*Y)^2 = g^2*T_j + 2g*(isx*pL - isy*pM)
//        + isx^2*pLL - 2*isx*isy*pLM + isy^2*pMM,  g = isx*O - isy*P,
//   T_j = 1024*j + 496,  Sx = sum_j (32*O_j + uL_j).
// R10: p1 at 16 waves/CU (1024 blocks, the R1 occupancy that measured fastest)
// x float2 width x full 9-moment set -- the last untested (waves,width) cell.
// All other cells plateau at ~3.0-3.3 TB/s delivered.

#define NT   4096
#define NP   4096
#define CH   128    // chunks
#define LCH  32     // rows per chunk; CH*LCH == NT
#define BLK  256

__global__ __launch_bounds__(BLK, 4) void p1_moments(
    const float* __restrict__ x, const float* __restrict__ y,
    float* __restrict__ aX, float* __restrict__ aY,
    float* __restrict__ uL, float* __restrict__ uM,
    float* __restrict__ pL, float* __restrict__ pM,
    float* __restrict__ pLL, float* __restrict__ pMM,
    float* __restrict__ pLM)
{
  const int pv = blockIdx.x * BLK + threadIdx.x;  // float2 column, 0..2047
  const int j  = blockIdx.y;                      // chunk
  const int t0 = j * LCH;
  const float2* xb = (const float2*)x + (size_t)t0 * (NP / 2) + pv;
  const float2* yb = (const float2*)y + (size_t)t0 * (NP / 2) + pv;

  float cx0 = 0.f, cx1 = 0.f, cy0 = 0.f, cy1 = 0.f;
  float uL0 = 0.f, uL1 = 0.f, uM0 = 0.f, uM1 = 0.f;
  float pL0 = 0.f, pL1 = 0.f, pM0 = 0.f, pM1 = 0.f;
  float pLL0 = 0.f, pLL1 = 0.f, pMM0 = 0.f, pMM1 = 0.f;
  float pLM0 = 0.f, pLM1 = 0.f;

#pragma unroll 8
  for (int i = 0; i < LCH; ++i) {
    const float2 xv = xb[(size_t)i * (NP / 2)];
    const float2 yv = yb[(size_t)i * (NP / 2)];
    const float t = (float)(t0 + i);

    const float lx0 = fmaxf(xv.x, 0.f), lx1 = fmaxf(xv.y, 0.f);
    const float ly0 = fmaxf(yv.x, 0.f), ly1 = fmaxf(yv.y, 0.f);

    cx0 += lx0; cy0 += ly0;
    const float tl0 = t * cx0, tm0 = t * cy0;
    pL0  += tl0;                  pM0  += tm0;
    pLL0 = fmaf(tl0, cx0, pLL0);  pMM0 = fmaf(tm0, cy0, pMM0);
    pLM0 = fmaf(tl0, cy0, pLM0);
    uL0  += cx0;                  uM0  += cy0;

    cx1 += lx1; cy1 += ly1;
    const float tl1 = t * cx1, tm1 = t * cy1;
    pL1  += tl1;                  pM1  += tm1;
    pLL1 = fmaf(tl1, cx1, pLL1);  pMM1 = fmaf(tm1, cy1, pMM1);
    pLM1 = fmaf(tl1, cy1, pLM1);
    uL1  += cx1;                  uM1  += cy1;
  }

  const size_t o2 = (size_t)j * (NP / 2) + pv;
  ((float2*)aX)[o2]  = make_float2(cx0, cx1);
  ((float2*)aY)[o2]  = make_float2(cy0, cy1);
  ((float2*)uL)[o2]  = make_float2(uL0, uL1);
  ((float2*)uM)[o2]  = make_float2(uM0, uM1);
  ((float2*)pL)[o2]  = make_float2(pL0, pL1);
  ((float2*)pM)[o2]  = make_float2(pM0, pM1);
  ((float2*)pLL)[o2] = make_float2(pLL0, pLL1);
  ((float2*)pMM)[o2] = make_float2(pMM0, pMM1);
  ((float2*)pLM)[o2] = make_float2(pLM0, pLM1);
}

// One wave per column p; lane handles chunks j0=2*lane, j0+1. (R9-verified.)
__global__ __launch_bounds__(BLK) void p2_loss(
    const float* __restrict__ aX, const float* __restrict__ aY,
    const float* __restrict__ uL, const float* __restrict__ uM,
    const float* __restrict__ pL, const float* __restrict__ pM,
    const float* __restrict__ pLL, const float* __restrict__ pMM,
    const float* __restrict__ pLM,
    double* __restrict__ part)
{
  const int wave = threadIdx.x >> 6;              // 4 waves per block
  const int lane = threadIdx.x & 63;
  const int p    = blockIdx.x * 4 + wave;
  const int j0   = 2 * lane;
  const size_t o0 = (size_t)j0 * NP + p;
  const size_t o1 = o0 + NP;

  const double a0 = (double)aX[o0], a1 = (double)aX[o1];
  const double b0 = (double)aY[o0], b1 = (double)aY[o1];
  const double ul0 = (double)uL[o0], ul1 = (double)uL[o1];
  const double um0 = (double)uM[o0], um1 = (double)uM[o1];

  // inclusive shuffle scan of per-lane sums -> exclusive lane offsets
  const double sA = a0 + a1, sB = b0 + b1;
  double ix = sA, iy = sB;
  for (int d = 1; d < 64; d <<= 1) {
    const double tx = __shfl_up(ix, d, 64);
    const double ty = __shfl_up(iy, d, 64);
    if (lane >= d) { ix += tx; iy += ty; }
  }
  const double O0 = ix - sA;        // offset before chunk j0
  const double P0 = iy - sB;
  const double O1 = O0 + a0;        // offset before chunk j0+1
  const double P1 = P0 + b0;

  // Sx = sum_j (32*O_j + uL_j), butterfly (all lanes get total)
  double vx = (double)LCH * (O0 + O1) + ul0 + ul1;
  double vy = (double)LCH * (P0 + P1) + um0 + um1;
  for (int m = 32; m; m >>= 1) {
    vx += __shfl_xor(vx, m, 64);
    vy += __shfl_xor(vy, m, 64);
  }
  const double isx = 1.0 / vx;
  const double isy = 1.0 / vy;

  // loss for the lane's two chunks
  double loss = 0.0;
  {
    const double g   = isx * O0 - isy * P0;
    const double Tj  = 1024.0 * (double)j0 + 496.0;
    const double sh  = isx * (double)pL[o0] - isy * (double)pM[o0];
    const double shh = isx * isx * (double)pLL[o0]
                     - 2.0 * isx * isy * (double)pLM[o0]
                     + isy * isy * (double)pMM[o0];
    loss += g * g * Tj + 2.0 * g * sh + shh;
  }
  {
    const double g   = isx * O1 - isy * P1;
    const double Tj  = 1024.0 * (double)(j0 + 1) + 496.0;
    const double sh  = isx * (double)pL[o1] - isy * (double)pM[o1];
    const double shh = isx * isx * (double)pLL[o1]
                     - 2.0 * isx * isy * (double)pLM[o1]
                     + isy * isy * (double)pMM[o1];
    loss += g * g * Tj + 2.0 * g * sh + shh;
  }

  for (int m = 32; m; m >>= 1) loss += __shfl_xor(loss, m, 64);
  if (lane == 0) part[p] = loss;
}

__global__ __launch_bounds__(1024) void p3_final(
    const double* __restrict__ part, float* __restrict__ out)
{
  __shared__ double red[1024];
  double v = 0.0;
  for (int i = threadIdx.x; i < NP; i += 1024) v += part[i];
  red[threadIdx.x] = v;
  __syncthreads();
  for (int s = 512; s > 0; s >>= 1) {
    if (threadIdx.x < s) red[threadIdx.x] += red[threadIdx.x + s];
    __syncthreads();
  }
  if (threadIdx.x == 0) out[0] = (float)red[0];
}

extern "C" void kernel_launch(void* const* d_in, const int* in_sizes, int n_in,
                              void* d_out, int out_size, void* d_ws, size_t ws_size,
                              hipStream_t stream) {
  const float* x = (const float*)d_in[0];
  const float* y = (const float*)d_in[1];
  float* out = (float*)d_out;

  const size_t CNP = (size_t)CH * NP;             // 512K elems per array
  char* ws = (char*)d_ws;
  float* aX  = (float*)ws; ws += CNP * sizeof(float);
  float* aY  = (float*)ws; ws += CNP * sizeof(float);
  float* uLp = (float*)ws; ws += CNP * sizeof(float);
  float* uMp = (float*)ws; ws += CNP * sizeof(float);
  float* pLp = (float*)ws; ws += CNP * sizeof(float);
  float* pMp = (float*)ws; ws += CNP * sizeof(float);
  float* pLLp = (float*)ws; ws += CNP * sizeof(float);
  float* pMMp = (float*)ws; ws += CNP * sizeof(float);
  float* pLMp = (float*)ws; ws += CNP * sizeof(float);
  double* part = (double*)ws; ws += (size_t)NP * sizeof(double);

  dim3 g1((NP / 2) / BLK, CH);                    // 8 x 128 = 1024 blocks
  p1_moments<<<g1, BLK, 0, stream>>>(x, y, aX, aY, uLp, uMp, pLp, pMp, pLLp, pMMp, pLMp);
  p2_loss<<<NP / 4, BLK, 0, stream>>>(aX, aY, uLp, uMp, pLp, pMp, pLLp, pMMp, pLMp, part);
  p3_final<<<1, 1024, 0, stream>>>(part, out);
}

// Round 11
// 164.375 us; speedup vs baseline: 1.1735x; 1.1735x over previous
//
#include <hip/hip_runtime.h>

// Sinkhorn loss, single-pass moment formulation — measured-best config (R4).
//   s_t = relu(v_t); X_t = cumsum(s); Sx = sum_t X_t
//   loss_p = sum_t t * (X_t/Sx - Y_t/Sy)^2 ;  out = sum_p loss_p
// Chunk j (LCH=64 rows; local cumsums L,M; exclusive offsets O,P):
//   sum_{t in j} t*(isx*X - isy*Y)^2 = g^2*T_j + 2g*(isx*pL - isy*pM)
//        + isx^2*pLL - 2*isx*isy*pLM + isy^2*pMM,  g = isx*O - isy*P.
// Evidence base (R1..R10): p1 delivered BW is invariant ~3.2 TB/s across
// waves/CU {8,16,32} x width {4,8,16B} x contiguity x batching — hierarchy-mix
// ceiling (50% L3-hit / 50% HBM + moment writes). This config sits on it.
// p2 = wave-per-column shuffle-scan combine (serial-load combine was 154 us).

#define NT   4096
#define NP   4096
#define CH   64     // number of t-chunks == wave size
#define LCH  64     // chunk length; CH*LCH == NT
#define BLK  256

__global__ __launch_bounds__(BLK) void p1_moments(
    const float* __restrict__ x, const float* __restrict__ y,
    float* __restrict__ aX, float* __restrict__ aY,
    float* __restrict__ uL, float* __restrict__ uM,
    float* __restrict__ pL, float* __restrict__ pM,
    float* __restrict__ pLL, float* __restrict__ pMM,
    float* __restrict__ pLM)
{
  const int pv = blockIdx.x * BLK + threadIdx.x;  // 0 .. NP/2-1 (float2 col)
  const int j  = blockIdx.y;
  const int t0 = j * LCH;
  const float2* xb = (const float2*)x + (size_t)t0 * (NP / 2) + pv;
  const float2* yb = (const float2*)y + (size_t)t0 * (NP / 2) + pv;

  float cx0 = 0.f, cx1 = 0.f, cy0 = 0.f, cy1 = 0.f;
  float uL0 = 0.f, uL1 = 0.f, uM0 = 0.f, uM1 = 0.f;
  float pL0 = 0.f, pL1 = 0.f, pM0 = 0.f, pM1 = 0.f;
  float pLL0 = 0.f, pLL1 = 0.f, pMM0 = 0.f, pMM1 = 0.f;
  float pLM0 = 0.f, pLM1 = 0.f;

#pragma unroll 8
  for (int i = 0; i < LCH; ++i) {
    const float2 xv = xb[(size_t)i * (NP / 2)];
    const float2 yv = yb[(size_t)i * (NP / 2)];
    const float t = (float)(t0 + i);

    const float lx0 = fmaxf(xv.x, 0.f), lx1 = fmaxf(xv.y, 0.f);
    const float ly0 = fmaxf(yv.x, 0.f), ly1 = fmaxf(yv.y, 0.f);

    cx0 += lx0; cy0 += ly0;
    const float tl0 = t * cx0, tm0 = t * cy0;
    pL0  += tl0;                  pM0  += tm0;
    pLL0 = fmaf(tl0, cx0, pLL0);  pMM0 = fmaf(tm0, cy0, pMM0);
    pLM0 = fmaf(tl0, cy0, pLM0);
    uL0  += cx0;                  uM0  += cy0;

    cx1 += lx1; cy1 += ly1;
    const float tl1 = t * cx1, tm1 = t * cy1;
    pL1  += tl1;                  pM1  += tm1;
    pLL1 = fmaf(tl1, cx1, pLL1);  pMM1 = fmaf(tm1, cy1, pMM1);
    pLM1 = fmaf(tl1, cy1, pLM1);
    uL1  += cx1;                  uM1  += cy1;
  }

  const size_t o2 = (size_t)j * (NP / 2) + pv;
  ((float2*)aX)[o2]  = make_float2(cx0, cx1);
  ((float2*)aY)[o2]  = make_float2(cy0, cy1);
  ((float2*)uL)[o2]  = make_float2(uL0, uL1);
  ((float2*)uM)[o2]  = make_float2(uM0, uM1);
  ((float2*)pL)[o2]  = make_float2(pL0, pL1);
  ((float2*)pM)[o2]  = make_float2(pM0, pM1);
  ((float2*)pLL)[o2] = make_float2(pLL0, pLL1);
  ((float2*)pMM)[o2] = make_float2(pMM0, pMM1);
  ((float2*)pLM)[o2] = make_float2(pLM0, pLM1);
}

// One wave per column p; lane = chunk j. Shuffle prefix scan for O/P.
__global__ __launch_bounds__(BLK) void p2_loss(
    const float* __restrict__ aX, const float* __restrict__ aY,
    const float* __restrict__ uL, const float* __restrict__ uM,
    const float* __restrict__ pL, const float* __restrict__ pM,
    const float* __restrict__ pLL, const float* __restrict__ pMM,
    const float* __restrict__ pLM,
    double* __restrict__ part)
{
  const int wave = threadIdx.x >> 6;           // 4 waves per block
  const int lane = threadIdx.x & 63;           // = chunk j
  const int p    = blockIdx.x * 4 + wave;
  const size_t o = (size_t)lane * NP + p;

  const double a  = (double)aX[o];
  const double b  = (double)aY[o];
  const double ul = (double)uL[o];
  const double um = (double)uM[o];

  // inclusive scan -> exclusive offsets
  double sx = a, sy = b;
  for (int d = 1; d < 64; d <<= 1) {
    const double tx = __shfl_up(sx, d, 64);
    const double ty = __shfl_up(sy, d, 64);
    if (lane >= d) { sx += tx; sy += ty; }
  }
  const double O = sx - a;
  const double P = sy - b;

  // Sx = sum_j (LCH*O_j + uL_j), butterfly reduce (all lanes get total)
  double vx = (double)LCH * O + ul;
  double vy = (double)LCH * P + um;
  for (int m = 32; m; m >>= 1) {
    vx += __shfl_xor(vx, m, 64);
    vy += __shfl_xor(vy, m, 64);
  }
  const double isx = 1.0 / vx;
  const double isy = 1.0 / vy;

  const double g   = isx * O - isy * P;
  const double Tj  = 4096.0 * (double)lane + 2016.0;
  const double sh  = isx * (double)pL[o] - isy * (double)pM[o];
  const double shh = isx * isx * (double)pLL[o]
                   - 2.0 * isx * isy * (double)pLM[o]
                   + isy * isy * (double)pMM[o];
  double loss = g * g * Tj + 2.0 * g * sh + shh;

  for (int m = 32; m; m >>= 1) loss += __shfl_xor(loss, m, 64);
  if (lane == 0) part[p] = loss;
}

__global__ __launch_bounds__(1024) void p3_final(
    const double* __restrict__ part, float* __restrict__ out)
{
  __shared__ double red[1024];
  double v = 0.0;
  for (int i = threadIdx.x; i < NP; i += 1024) v += part[i];
  red[threadIdx.x] = v;
  __syncthreads();
  for (int s = 512; s > 0; s >>= 1) {
    if (threadIdx.x < s) red[threadIdx.x] += red[threadIdx.x + s];
    __syncthreads();
  }
  if (threadIdx.x == 0) out[0] = (float)red[0];
}

extern "C" void kernel_launch(void* const* d_in, const int* in_sizes, int n_in,
                              void* d_out, int out_size, void* d_ws, size_t ws_size,
                              hipStream_t stream) {
  const float* x = (const float*)d_in[0];
  const float* y = (const float*)d_in[1];
  float* out = (float*)d_out;

  const size_t CNP = (size_t)CH * NP;
  char* ws = (char*)d_ws;
  float* aX  = (float*)ws; ws += CNP * sizeof(float);
  float* aY  = (float*)ws; ws += CNP * sizeof(float);
  float* uLp = (float*)ws; ws += CNP * sizeof(float);
  float* uMp = (float*)ws; ws += CNP * sizeof(float);
  float* pLp = (float*)ws; ws += CNP * sizeof(float);
  float* pMp = (float*)ws; ws += CNP * sizeof(float);
  float* pLLp = (float*)ws; ws += CNP * sizeof(float);
  float* pMMp = (float*)ws; ws += CNP * sizeof(float);
  float* pLMp = (float*)ws; ws += CNP * sizeof(float);
  double* part = (double*)ws; ws += (size_t)NP * sizeof(double);

  dim3 g1((NP / 2) / BLK, CH);  // 8 x 64 blocks, 2048 waves
  p1_moments<<<g1, BLK, 0, stream>>>(x, y, aX, aY, uLp, uMp, pLp, pMp, pLLp, pMMp, pLMp);
  p2_loss<<<NP / 4, BLK, 0, stream>>>(aX, aY, uLp, uMp, pLp, pMp, pLLp, pMMp, pLMp, part);
  p3_final<<<1, 1024, 0, stream>>>(part, out);
}